// Round 6
// baseline (194.635 us; speedup 1.0000x reference)
//
#include <hip/hip_runtime.h>
#include <cstdint>
#include <cstddef>

typedef __attribute__((ext_vector_type(8))) short short8;   // 8 bf16 = 4 VGPRs (MFMA A/B frag)
typedef __attribute__((ext_vector_type(4))) float floatx4;  // MFMA C/D frag

__device__ __forceinline__ float bf2f(unsigned short u) {
  union { unsigned int i; float f; } c; c.i = ((unsigned int)u) << 16; return c.f;
}
__device__ __forceinline__ unsigned short f2bf(float f) {
  union { float f; unsigned int i; } c; c.f = f;
  unsigned int r = c.i + 0x7fffu + ((c.i >> 16) & 1u);  // round-nearest-even
  return (unsigned short)(r >> 16);
}
__device__ __forceinline__ unsigned int fbits(float f) {
  union { float f; unsigned int i; } c; c.f = f; return c.i;
}

// async global->LDS, 16 B per lane; LDS dest = wave-uniform base + lane*16 (m97/m104)
__device__ __forceinline__ void glds16(const unsigned short* g, unsigned short* l) {
  __builtin_amdgcn_global_load_lds((const __attribute__((address_space(1))) void*)g,
                                   (__attribute__((address_space(3))) void*)l, 16, 0, 0);
}

// ---- 32x32 transpose+cvt tile helper (256 threads, 4 rows/thread) ----
__device__ __forceinline__ void tr_tile(const float* __restrict__ in,
                                        unsigned short* __restrict__ out,
                                        int R, int C, int bx, int by, int tid,
                                        unsigned short (*t)[33]) {
  const int cx = tid & 31, rl = tid >> 5;
#pragma unroll
  for (int i = 0; i < 4; ++i)
    t[rl + i * 8][cx] = f2bf(in[(size_t)(by * 32 + rl + i * 8) * C + bx * 32 + cx]);
  __syncthreads();
  const int oc = by * 32 + cx;
#pragma unroll
  for (int i = 0; i < 4; ++i)
    out[(size_t)(bx * 32 + rl + i * 8) * R + oc] = t[cx][rl + i * 8];
}

// ---- fused prep: W_qkv^T (3072 blks) + W_out^T (1024 blks) + x cvt (4096 blks) ----
__global__ __launch_bounds__(256) void k_prep(const float* __restrict__ x,
                                              const float* __restrict__ Wq,
                                              const float* __restrict__ Wo,
                                              unsigned short* __restrict__ x_bf,
                                              unsigned short* __restrict__ WTq,
                                              unsigned short* __restrict__ WTo) {
  __shared__ unsigned short t[32][33];
  const int bid = blockIdx.x, tid = threadIdx.x;
  if (bid < 3072) {
    tr_tile(Wq, WTq, 1024, 3072, bid % 96, bid / 96, tid, t);
  } else if (bid < 4096) {
    int v = bid - 3072;
    tr_tile(Wo, WTo, 1024, 1024, v & 31, v >> 5, tid, t);
  } else {
    int i = (bid - 4096) * 256 + tid;
    float4 v = ((const float4*)x)[i];
    ushort4 o = { f2bf(v.x), f2bf(v.y), f2bf(v.z), f2bf(v.w) };
    ((ushort4*)x_bf)[i] = o;
  }
}

// ---------------- GEMM: C[M][N] = A[M][K] * BT[N][K]^T, bf16 in ----------------
// m97 structure + r9: BK=64 via TWO glds16 buffers -> one barrier pair per
// 64-K instead of 32-K (halves barrier-drain stalls). LDS 32 KB.
template <int MT, bool F32OUT>
__global__ __launch_bounds__(256) void k_gemm_bt(const unsigned short* __restrict__ A,
                                                 const unsigned short* __restrict__ BT,
                                                 void* __restrict__ Cout,
                                                 int M, int N, int K) {
  constexpr int NI = MT / 32;  // per-wave m-frag count (4 or 2)
  __shared__ unsigned short As[2][MT * 32];
  __shared__ unsigned short Bs[2][128 * 32];
  const int bm = blockIdx.x * MT, bn = blockIdx.y * 128;
  const int tid = threadIdx.x;
  const int wave = tid >> 6, lane = tid & 63;
  const int wm = (wave & 1) * (MT / 2), wn = (wave >> 1) * 64;
  const int lrow = lane & 15, lgrp = lane >> 4;
  floatx4 acc[NI][4] = {};

  const int lr4 = lane >> 2, lc8 = (lane & 3) * 8;
  const int br0 = wave * 32;
  const unsigned short* Bg0 = BT + (size_t)(bn + br0 + lr4) * K + lc8;
  const unsigned short* Bg1 = BT + (size_t)(bn + br0 + 16 + lr4) * K + lc8;
  const int ar0 = wave * (MT / 4);
  const unsigned short* Ag0 = A + (size_t)(bm + ar0 + lr4) * K + lc8;
  const unsigned short* Ag1 = A + (size_t)(bm + ar0 + 16 + lr4) * K + lc8;  // MT==128 only

  for (int k0 = 0; k0 < K; k0 += 64) {
#pragma unroll
    for (int u = 0; u < 2; ++u) {
      const int ko = k0 + u * 32;
      glds16(Ag0 + ko, &As[u][ar0 * 32]);
      if (MT == 128) glds16(Ag1 + ko, &As[u][(ar0 + 16) * 32]);
      glds16(Bg0 + ko, &Bs[u][br0 * 32]);
      glds16(Bg1 + ko, &Bs[u][(br0 + 16) * 32]);
    }
    __syncthreads();   // drains vmcnt (glds) before any wave reads LDS
#pragma unroll
    for (int u = 0; u < 2; ++u) {
      short8 a[NI], bfr[4];
#pragma unroll
      for (int i = 0; i < NI; ++i)
        a[i] = *(const short8*)&As[u][(wm + i * 16 + lrow) * 32 + lgrp * 8];
#pragma unroll
      for (int j = 0; j < 4; ++j)
        bfr[j] = *(const short8*)&Bs[u][(wn + j * 16 + lrow) * 32 + lgrp * 8];
#pragma unroll
      for (int i = 0; i < NI; ++i)
#pragma unroll
        for (int j = 0; j < 4; ++j)
          acc[i][j] = __builtin_amdgcn_mfma_f32_16x16x32_bf16(a[i], bfr[j], acc[i][j], 0, 0, 0);
    }
    __syncthreads();
  }
#pragma unroll
  for (int i = 0; i < NI; ++i)
#pragma unroll
    for (int j = 0; j < 4; ++j)
#pragma unroll
      for (int r = 0; r < 4; ++r) {
        int m = bm + wm + i * 16 + lgrp * 4 + r;
        int n = bn + wn + j * 16 + lrow;
        if (F32OUT)
          ((float*)Cout)[(size_t)m * N + n] = acc[i][j][r];
        else
          ((unsigned short*)Cout)[(size_t)m * N + n] = f2bf(acc[i][j][r]);
      }
}

// ---- fused LN (4096 blks) + V transpose (4096 blks); both read qkv ----
// LN: q out folded by 0.125*log2(e) so flash uses exp2 directly.
__global__ __launch_bounds__(256) void k_lnv(const unsigned short* __restrict__ qkv,
                                             const float* __restrict__ q_scale,
                                             const float* __restrict__ k_scale,
                                             unsigned short* __restrict__ q_n,
                                             unsigned short* __restrict__ k_n,
                                             unsigned short* __restrict__ VT) {
  const int bid = blockIdx.x, tid = threadIdx.x;
  if (bid < 4096) {
    const int tok = bid;
    const int wave = tid >> 6, lane = tid & 63;
    __shared__ float red[2][4];
    const unsigned short* row = qkv + (size_t)tok * 3072;
#pragma unroll
    for (int seg = 0; seg < 2; ++seg) {
      const unsigned short* p  = row + seg * 1024;
      const float* sc = seg ? k_scale : q_scale;
      unsigned short* outp = (seg ? k_n : q_n) + (size_t)tok * 1024;
      ushort4 u = *(const ushort4*)&p[tid * 4];
      float xv[4] = { bf2f(u.x), bf2f(u.y), bf2f(u.z), bf2f(u.w) };
      float sum = xv[0] + xv[1] + xv[2] + xv[3];
      float sq  = xv[0]*xv[0] + xv[1]*xv[1] + xv[2]*xv[2] + xv[3]*xv[3];
      for (int off = 32; off; off >>= 1) {
        sum += __shfl_down(sum, off, 64);
        sq  += __shfl_down(sq,  off, 64);
      }
      if (lane == 0) { red[0][wave] = sum; red[1][wave] = sq; }
      __syncthreads();
      sum = red[0][0] + red[0][1] + red[0][2] + red[0][3];
      sq  = red[1][0] + red[1][1] + red[1][2] + red[1][3];
      __syncthreads();
      float mean = sum * (1.0f / 1024.0f);
      float var  = sq * (1.0f / 1024.0f) - mean * mean;
      float rstd = rsqrtf(var + 1e-6f);
      if (seg == 0) rstd *= 0.18033688011112042f;  // 0.125 * log2(e)
      float4 su = *(const float4*)&sc[tid * 4];
      ushort4 o;
      o.x = f2bf((xv[0] - mean) * rstd * su.x);
      o.y = f2bf((xv[1] - mean) * rstd * su.y);
      o.z = f2bf((xv[2] - mean) * rstd * su.z);
      o.w = f2bf((xv[3] - mean) * rstd * su.w);
      *(ushort4*)&outp[tid * 4] = o;
    }
  } else {
    // V transpose tile: v-part [b,s,h*64+hd] -> VT[(b*16+h)*64+hd][s]
    __shared__ unsigned short t[32][33];
    const int v = bid - 4096;
    const int bh = v & 31, b = bh >> 4, h = bh & 15;
    const int sy = (v >> 5) & 63, hx = v >> 11;   // s-tile 0..63, hd-tile 0..1
    const int cx = tid & 31, rl = tid >> 5;
#pragma unroll
    for (int i = 0; i < 4; ++i)
      t[rl + i * 8][cx] =
        qkv[(size_t)(b * 2048 + sy * 32 + rl + i * 8) * 3072 + 2048 + h * 64 + hx * 32 + cx];
    __syncthreads();
#pragma unroll
    for (int i = 0; i < 4; ++i)
      VT[((size_t)bh * 64 + hx * 32 + rl + i * 8) * 2048 + sy * 32 + cx] = t[cx][rl + i * 8];
  }
}

// ------------------------------ flash attention ------------------------------
// r16 = r15 (ones-trick l on MFMA pipe, v_perm pack, fixed-max softmax) with
// the t-step HALVED 128 -> 64. Diagnosis: exp2 (quarter-rate TRANS, 32/step)
// is ~2x the MFMA time; TRANS<->MFMA only overlap ACROSS waves, and occupancy
// was LDS-capped at 24% (53248 B -> 3 blocks/CU). Halving the step shrinks
// Ks 64x72 + Vs 64x72 + Ps 2x32x72 = 27648 B -> 5 blocks/CU (20 waves/CU,
// VGPR 84 <= 102 cap). Same bytes staged / MFMA / exp per unit work; barriers
// per work double — the bet is cross-block overlap absorbs them (m114).
// Bonuses: no half-step waste (64 | tend), only the diagonal step masked,
// and a by->qt swizzle making every CU's step-sum uniform (66) since all
// 1024 blocks are resident in one generation at 4-5 blocks/CU.
// All b128 LDS strides multiples of 8 shorts (16 B) — r6 lesson.

#define KS_STRIDE 72   // 64 hd + 8 pad = 144 B = 9*16
#define VS_STRIDE 72   // 64 t  + 8 pad
#define PS_STRIDE 72   // per-wq [32 q][64 t] pad->72

#define MFMA_BF16 __builtin_amdgcn_mfma_f32_16x16x32_bf16

template <bool MASKED>
__device__ __forceinline__ void attn_step(int t0, int q0, int wq, int wt,
    const short8 (&qa)[2][2],
    const unsigned short* Ks, const unsigned short* Vs, unsigned short* Psq,
    floatx4 (&o)[2][4], floatx4 (&o_l)[2], int lrow, int lgrp) {
  const int twbase = wt * 32;   // this wave's 32-t slice of the 64-t tile
#pragma unroll
  for (int tb = 0; tb < 2; ++tb) {
    short8 kb0 = *(const short8*)&Ks[(twbase + tb * 16 + lrow) * KS_STRIDE + lgrp * 8];
    short8 kb1 = *(const short8*)&Ks[(twbase + tb * 16 + lrow) * KS_STRIDE + 32 + lgrp * 8];
#pragma unroll
    for (int qb = 0; qb < 2; ++qb) {
      floatx4 st = {};
      st = MFMA_BF16(kb0, qa[qb][0], st, 0, 0, 0);
      st = MFMA_BF16(kb1, qa[qb][1], st, 0, 0, 0);
      // C layout: lane holds t = twbase+tb*16+lgrp*4+r (row), q = qb*16+lrow (col)
      float p0 = exp2f(st[0]), p1 = exp2f(st[1]);
      float p2 = exp2f(st[2]), p3 = exp2f(st[3]);
      if (MASKED) {
        const int qcol = q0 + wq * 32 + qb * 16 + lrow;
        const int tbase = t0 + twbase + tb * 16 + lgrp * 4;
        p0 = (tbase     <= qcol) ? p0 : 0.0f;
        p1 = (tbase + 1 <= qcol) ? p1 : 0.0f;
        p2 = (tbase + 2 <= qcol) ? p2 : 0.0f;
        p3 = (tbase + 3 <= qcol) ? p3 : 0.0f;
      }
      // trunc-pack two bf16 highs in one v_perm_b32 each (no VALU l-accum)
      uint2 pu;
      pu.x = __builtin_amdgcn_perm(fbits(p1), fbits(p0), 0x07060302u);
      pu.y = __builtin_amdgcn_perm(fbits(p3), fbits(p2), 0x07060302u);
      *(uint2*)&Psq[(qb * 16 + lrow) * PS_STRIDE + twbase + tb * 16 + lgrp * 4] = pu;
    }
  }
  // PV over this wave's 32-t slice: A = P[q][t] (own cols), B = V[t][hd].
  // l via B=ones: o_l[qb][r] = partial sum_t P[q][t], same layout as o.
  const short8 vones = { 0x3F80, 0x3F80, 0x3F80, 0x3F80,
                         0x3F80, 0x3F80, 0x3F80, 0x3F80 };  // bf16 1.0 x8
  short8 pa0 = *(const short8*)&Psq[lrow * PS_STRIDE + twbase + lgrp * 8];
  short8 pa1 = *(const short8*)&Psq[(16 + lrow) * PS_STRIDE + twbase + lgrp * 8];
  o_l[0] = MFMA_BF16(pa0, vones, o_l[0], 0, 0, 0);
  o_l[1] = MFMA_BF16(pa1, vones, o_l[1], 0, 0, 0);
#pragma unroll
  for (int hb = 0; hb < 4; ++hb) {
    short8 vb = *(const short8*)&Vs[(hb * 16 + lrow) * VS_STRIDE + twbase + lgrp * 8];
    o[0][hb] = MFMA_BF16(pa0, vb, o[0][hb], 0, 0, 0);
    o[1][hb] = MFMA_BF16(pa1, vb, o[1][hb], 0, 0, 0);
  }
}

// grid (32 bh, 32 by): linear id % 8 = bh % 8 -> one bh per XCD (L2 locality).
// by->qt swizzle: round-robin CU assignment gets by = {b,b+8,b+16,b+24};
// qt = 8j + (j odd ? 7-i : i) makes each CU's total steps = 66 (uniform).
// block 256 = 4 waves (2q x 2t). LDS 27648 B -> 14 granules -> 5 blocks/CU.
__global__ __launch_bounds__(256) void k_flash(const unsigned short* __restrict__ q_n,
                                               const unsigned short* __restrict__ k_n,
                                               const unsigned short* __restrict__ VT,
                                               unsigned short* __restrict__ ctx) {
  const int S = 2048, D = 1024;
  const int bh = blockIdx.x, b = bh >> 4, h = bh & 15;
  const int byi = (int)blockIdx.y, bi = byi & 7, bj = byi >> 3;
  const int qt = 8 * bj + ((bj & 1) ? (7 - bi) : bi);
  const int q0 = qt * 64;
  const int tid = threadIdx.x, wave = tid >> 6, lane = tid & 63;
  const int wq = wave >> 1, wt = wave & 1;
  const int lrow = lane & 15, lgrp = lane >> 4;

  __shared__ __align__(16) unsigned char smem[27648];
  unsigned short* Ks  = (unsigned short*)smem;                    // 64*72*2 =  9216
  unsigned short* Vs  = (unsigned short*)(smem + 9216);           // 64*72*2 =  9216
  unsigned short* Psq = (unsigned short*)(smem + 18432) + wq * 32 * PS_STRIDE; // 2*4608
  // tail aliases (dead after final barrier): buf over Ks/Vs, Lbuf after
  float* buf  = (float*)smem;                                     // 2*32*68*4 = 17408
  float* Lbuf = (float*)(smem + 17408);                           // 64 floats -> 17664

  const unsigned short* kg = k_n + (size_t)(b * S) * D + h * 64;
  const unsigned short* vg = VT + (size_t)bh * 64 * S;
  const int sr = tid >> 3, sc = (tid & 7) * 8;   // staging: 32 rows/pass, 2 passes

  // qa[qb]: B-frag, lane n = q = q0 + wq*32 + qb*16 + lrow, k = hd = lgrp*8+j (+32)
  short8 qa[2][2];
#pragma unroll
  for (int qb = 0; qb < 2; ++qb) {
    const unsigned short* qp =
        q_n + (size_t)(b * S + q0 + wq * 32 + qb * 16 + lrow) * D + h * 64;
    qa[qb][0] = *(const short8*)(qp + lgrp * 8);
    qa[qb][1] = *(const short8*)(qp + 32 + lgrp * 8);
  }
  floatx4 o[2][4] = {};
  floatx4 o_l[2] = {};

  const int tend = q0 + 64;
  for (int t0 = 0; t0 < tend; t0 += 64) {
    // K: 64 t-rows x 64 hd; V: 64 hd-rows x 64 t (2 int4 per thread each)
    *(int4*)&Ks[sr * KS_STRIDE + sc]        = *(const int4*)(kg + (size_t)(t0 + sr) * D + sc);
    *(int4*)&Ks[(sr + 32) * KS_STRIDE + sc] = *(const int4*)(kg + (size_t)(t0 + sr + 32) * D + sc);
    *(int4*)&Vs[sr * VS_STRIDE + sc]        = *(const int4*)(vg + (size_t)sr * S + t0 + sc);
    *(int4*)&Vs[(sr + 32) * VS_STRIDE + sc] = *(const int4*)(vg + (size_t)(sr + 32) * S + t0 + sc);
    __syncthreads();
    if (t0 + 64 <= q0)
      attn_step<false>(t0, q0, wq, wt, qa, Ks, Vs, Psq, o, o_l, lrow, lgrp);
    else
      attn_step<true>(t0, q0, wq, wt, qa, Ks, Vs, Psq, o, o_l, lrow, lgrp);
    __syncthreads();
  }

  // ---- tail: combine the wt pair (O and l are t-partial per wave) ----
  // o_l[qb][r] = partial l for q-row qb*16+lgrp*4+r, replicated over lrow.
  if (wt == 1) {
    if (lrow == 0) {
#pragma unroll
      for (int qb = 0; qb < 2; ++qb)
#pragma unroll
        for (int r = 0; r < 4; ++r)
          Lbuf[wq * 32 + qb * 16 + lgrp * 4 + r] = o_l[qb][r];
    }
    float* bf = buf + wq * 32 * 68;
#pragma unroll
    for (int qb = 0; qb < 2; ++qb)
#pragma unroll
      for (int hb = 0; hb < 4; ++hb)
#pragma unroll
        for (int r = 0; r < 4; ++r)
          bf[(qb * 16 + lgrp * 4 + r) * 68 + hb * 16 + lrow] = o[qb][hb][r];
  }
  __syncthreads();
  if (wt == 0) {
    float* bf = buf + wq * 32 * 68;
#pragma unroll
    for (int qb = 0; qb < 2; ++qb)
#pragma unroll
      for (int hb = 0; hb < 4; ++hb)
#pragma unroll
        for (int r = 0; r < 4; ++r)
          o[qb][hb][r] += bf[(qb * 16 + lgrp * 4 + r) * 68 + hb * 16 + lrow];
    unsigned short* op = ctx + (size_t)(b * S + q0 + wq * 32) * D + h * 64;
#pragma unroll
    for (int qb = 0; qb < 2; ++qb)
#pragma unroll
      for (int r = 0; r < 4; ++r) {
        float inv = 1.0f / (o_l[qb][r] + Lbuf[wq * 32 + qb * 16 + lgrp * 4 + r]);
        int row = qb * 16 + lgrp * 4 + r;
#pragma unroll
        for (int hb = 0; hb < 4; ++hb)
          op[(size_t)row * D + hb * 16 + lrow] = f2bf(o[qb][hb][r] * inv);
      }
  }
}

// ---------------------------------- launch ----------------------------------
extern "C" void kernel_launch(void* const* d_in, const int* in_sizes, int n_in,
                              void* d_out, int out_size, void* d_ws, size_t ws_size,
                              hipStream_t stream) {
  const float* x       = (const float*)d_in[0];   // [2,2048,1024] fp32
  const float* W_qkv   = (const float*)d_in[1];   // [1024,3072] fp32
  const float* q_scale = (const float*)d_in[2];   // [1024] fp32
  const float* k_scale = (const float*)d_in[3];   // [1024] fp32
  const float* W_out   = (const float*)d_in[4];   // [1024,1024] fp32
  float* out = (float*)d_out;                     // [2,2048,1024] fp32
  char* ws = (char*)d_ws;
  unsigned short* WT_qkv = (unsigned short*)(ws + 0);         //  6291456
  unsigned short* WT_out = (unsigned short*)(ws + 6291456);   //  2097152
  unsigned short* qkv    = (unsigned short*)(ws + 8388608);   // 25165824
  unsigned short* q_nb   = (unsigned short*)(ws + 33554432);  //  8388608
  unsigned short* k_nb   = (unsigned short*)(ws + 41943040);  //  8388608
  unsigned short* VT     = (unsigned short*)(ws + 50331648);  //  8388608
  unsigned short* x_bf   = (unsigned short*)(ws + 58720256);  //  8388608 -> 64 MiB
  unsigned short* ctx    = qkv;  // alias: qkv dead after k_lnv

  k_prep<<<8192, 256, 0, stream>>>(x, W_qkv, W_out, x_bf, WT_qkv, WT_out);
  k_gemm_bt<128, false><<<dim3(32, 24), 256, 0, stream>>>(x_bf, WT_qkv, qkv, 4096, 3072, 1024);
  k_lnv<<<8192, 256, 0, stream>>>(qkv, q_scale, k_scale, q_nb, k_nb, VT);
  k_flash<<<dim3(32, 32), 256, 0, stream>>>(q_nb, k_nb, VT, ctx);
  k_gemm_bt<64, true><<<dim3(64, 8), 256, 0, stream>>>(ctx, WT_out, out, 4096, 1024, 1024);
}

// Round 7
// 185.514 us; speedup vs baseline: 1.0492x; 1.0492x over previous
//
#include <hip/hip_runtime.h>
#include <cstdint>
#include <cstddef>

typedef __attribute__((ext_vector_type(8))) short short8;   // 8 bf16 = 4 VGPRs (MFMA A/B frag)
typedef __attribute__((ext_vector_type(4))) float floatx4;  // MFMA C/D frag

__device__ __forceinline__ float bf2f(unsigned short u) {
  union { unsigned int i; float f; } c; c.i = ((unsigned int)u) << 16; return c.f;
}
__device__ __forceinline__ unsigned short f2bf(float f) {
  union { float f; unsigned int i; } c; c.f = f;
  unsigned int r = c.i + 0x7fffu + ((c.i >> 16) & 1u);  // round-nearest-even
  return (unsigned short)(r >> 16);
}
__device__ __forceinline__ unsigned int fbits(float f) {
  union { float f; unsigned int i; } c; c.f = f; return c.i;
}

// async global->LDS, 16 B per lane; LDS dest = wave-uniform base + lane*16 (m97/m104)
__device__ __forceinline__ void glds16(const unsigned short* g, unsigned short* l) {
  __builtin_amdgcn_global_load_lds((const __attribute__((address_space(1))) void*)g,
                                   (__attribute__((address_space(3))) void*)l, 16, 0, 0);
}

// ---- 32x32 transpose+cvt tile helper (256 threads, 4 rows/thread) ----
__device__ __forceinline__ void tr_tile(const float* __restrict__ in,
                                        unsigned short* __restrict__ out,
                                        int R, int C, int bx, int by, int tid,
                                        unsigned short (*t)[33]) {
  const int cx = tid & 31, rl = tid >> 5;
#pragma unroll
  for (int i = 0; i < 4; ++i)
    t[rl + i * 8][cx] = f2bf(in[(size_t)(by * 32 + rl + i * 8) * C + bx * 32 + cx]);
  __syncthreads();
  const int oc = by * 32 + cx;
#pragma unroll
  for (int i = 0; i < 4; ++i)
    out[(size_t)(bx * 32 + rl + i * 8) * R + oc] = t[cx][rl + i * 8];
}

// ---- fused prep: W_qkv^T (3072 blks) + W_out^T (1024 blks) + x cvt (4096 blks) ----
__global__ __launch_bounds__(256) void k_prep(const float* __restrict__ x,
                                              const float* __restrict__ Wq,
                                              const float* __restrict__ Wo,
                                              unsigned short* __restrict__ x_bf,
                                              unsigned short* __restrict__ WTq,
                                              unsigned short* __restrict__ WTo) {
  __shared__ unsigned short t[32][33];
  const int bid = blockIdx.x, tid = threadIdx.x;
  if (bid < 3072) {
    tr_tile(Wq, WTq, 1024, 3072, bid % 96, bid / 96, tid, t);
  } else if (bid < 4096) {
    int v = bid - 3072;
    tr_tile(Wo, WTo, 1024, 1024, v & 31, v >> 5, tid, t);
  } else {
    int i = (bid - 4096) * 256 + tid;
    float4 v = ((const float4*)x)[i];
    ushort4 o = { f2bf(v.x), f2bf(v.y), f2bf(v.z), f2bf(v.w) };
    ((ushort4*)x_bf)[i] = o;
  }
}

// ---------------- GEMM: C[M][N] = A[M][K] * BT[N][K]^T, bf16 in ----------------
// m97 structure + r9: BK=64 via TWO glds16 buffers -> one barrier pair per
// 64-K instead of 32-K (halves barrier-drain stalls). LDS 32 KB.
template <int MT, bool F32OUT>
__global__ __launch_bounds__(256) void k_gemm_bt(const unsigned short* __restrict__ A,
                                                 const unsigned short* __restrict__ BT,
                                                 void* __restrict__ Cout,
                                                 int M, int N, int K) {
  constexpr int NI = MT / 32;  // per-wave m-frag count (4 or 2)
  __shared__ unsigned short As[2][MT * 32];
  __shared__ unsigned short Bs[2][128 * 32];
  const int bm = blockIdx.x * MT, bn = blockIdx.y * 128;
  const int tid = threadIdx.x;
  const int wave = tid >> 6, lane = tid & 63;
  const int wm = (wave & 1) * (MT / 2), wn = (wave >> 1) * 64;
  const int lrow = lane & 15, lgrp = lane >> 4;
  floatx4 acc[NI][4] = {};

  const int lr4 = lane >> 2, lc8 = (lane & 3) * 8;
  const int br0 = wave * 32;
  const unsigned short* Bg0 = BT + (size_t)(bn + br0 + lr4) * K + lc8;
  const unsigned short* Bg1 = BT + (size_t)(bn + br0 + 16 + lr4) * K + lc8;
  const int ar0 = wave * (MT / 4);
  const unsigned short* Ag0 = A + (size_t)(bm + ar0 + lr4) * K + lc8;
  const unsigned short* Ag1 = A + (size_t)(bm + ar0 + 16 + lr4) * K + lc8;  // MT==128 only

  for (int k0 = 0; k0 < K; k0 += 64) {
#pragma unroll
    for (int u = 0; u < 2; ++u) {
      const int ko = k0 + u * 32;
      glds16(Ag0 + ko, &As[u][ar0 * 32]);
      if (MT == 128) glds16(Ag1 + ko, &As[u][(ar0 + 16) * 32]);
      glds16(Bg0 + ko, &Bs[u][br0 * 32]);
      glds16(Bg1 + ko, &Bs[u][(br0 + 16) * 32]);
    }
    __syncthreads();   // drains vmcnt (glds) before any wave reads LDS
#pragma unroll
    for (int u = 0; u < 2; ++u) {
      short8 a[NI], bfr[4];
#pragma unroll
      for (int i = 0; i < NI; ++i)
        a[i] = *(const short8*)&As[u][(wm + i * 16 + lrow) * 32 + lgrp * 8];
#pragma unroll
      for (int j = 0; j < 4; ++j)
        bfr[j] = *(const short8*)&Bs[u][(wn + j * 16 + lrow) * 32 + lgrp * 8];
#pragma unroll
      for (int i = 0; i < NI; ++i)
#pragma unroll
        for (int j = 0; j < 4; ++j)
          acc[i][j] = __builtin_amdgcn_mfma_f32_16x16x32_bf16(a[i], bfr[j], acc[i][j], 0, 0, 0);
    }
    __syncthreads();
  }
#pragma unroll
  for (int i = 0; i < NI; ++i)
#pragma unroll
    for (int j = 0; j < 4; ++j)
#pragma unroll
      for (int r = 0; r < 4; ++r) {
        int m = bm + wm + i * 16 + lgrp * 4 + r;
        int n = bn + wn + j * 16 + lrow;
        if (F32OUT)
          ((float*)Cout)[(size_t)m * N + n] = acc[i][j][r];
        else
          ((unsigned short*)Cout)[(size_t)m * N + n] = f2bf(acc[i][j][r]);
      }
}

// ---- fused LN (4096 blks) + V transpose (4096 blks); both read qkv ----
// LN: q out folded by 0.125*log2(e) so flash uses exp2 directly.
__global__ __launch_bounds__(256) void k_lnv(const unsigned short* __restrict__ qkv,
                                             const float* __restrict__ q_scale,
                                             const float* __restrict__ k_scale,
                                             unsigned short* __restrict__ q_n,
                                             unsigned short* __restrict__ k_n,
                                             unsigned short* __restrict__ VT) {
  const int bid = blockIdx.x, tid = threadIdx.x;
  if (bid < 4096) {
    const int tok = bid;
    const int wave = tid >> 6, lane = tid & 63;
    __shared__ float red[2][4];
    const unsigned short* row = qkv + (size_t)tok * 3072;
#pragma unroll
    for (int seg = 0; seg < 2; ++seg) {
      const unsigned short* p  = row + seg * 1024;
      const float* sc = seg ? k_scale : q_scale;
      unsigned short* outp = (seg ? k_n : q_n) + (size_t)tok * 1024;
      ushort4 u = *(const ushort4*)&p[tid * 4];
      float xv[4] = { bf2f(u.x), bf2f(u.y), bf2f(u.z), bf2f(u.w) };
      float sum = xv[0] + xv[1] + xv[2] + xv[3];
      float sq  = xv[0]*xv[0] + xv[1]*xv[1] + xv[2]*xv[2] + xv[3]*xv[3];
      for (int off = 32; off; off >>= 1) {
        sum += __shfl_down(sum, off, 64);
        sq  += __shfl_down(sq,  off, 64);
      }
      if (lane == 0) { red[0][wave] = sum; red[1][wave] = sq; }
      __syncthreads();
      sum = red[0][0] + red[0][1] + red[0][2] + red[0][3];
      sq  = red[1][0] + red[1][1] + red[1][2] + red[1][3];
      __syncthreads();
      float mean = sum * (1.0f / 1024.0f);
      float var  = sq * (1.0f / 1024.0f) - mean * mean;
      float rstd = rsqrtf(var + 1e-6f);
      if (seg == 0) rstd *= 0.18033688011112042f;  // 0.125 * log2(e)
      float4 su = *(const float4*)&sc[tid * 4];
      ushort4 o;
      o.x = f2bf((xv[0] - mean) * rstd * su.x);
      o.y = f2bf((xv[1] - mean) * rstd * su.y);
      o.z = f2bf((xv[2] - mean) * rstd * su.z);
      o.w = f2bf((xv[3] - mean) * rstd * su.w);
      *(ushort4*)&outp[tid * 4] = o;
    }
  } else {
    // V transpose tile: v-part [b,s,h*64+hd] -> VT[(b*16+h)*64+hd][s]
    __shared__ unsigned short t[32][33];
    const int v = bid - 4096;
    const int bh = v & 31, b = bh >> 4, h = bh & 15;
    const int sy = (v >> 5) & 63, hx = v >> 11;   // s-tile 0..63, hd-tile 0..1
    const int cx = tid & 31, rl = tid >> 5;
#pragma unroll
    for (int i = 0; i < 4; ++i)
      t[rl + i * 8][cx] =
        qkv[(size_t)(b * 2048 + sy * 32 + rl + i * 8) * 3072 + 2048 + h * 64 + hx * 32 + cx];
    __syncthreads();
#pragma unroll
    for (int i = 0; i < 4; ++i)
      VT[((size_t)bh * 64 + hx * 32 + rl + i * 8) * 2048 + sy * 32 + cx] = t[cx][rl + i * 8];
  }
}

// ------------------------------ flash attention ------------------------------
// r17: K/V staging via global_load_lds + both-sides XOR swizzle + double
// buffer + ONE barrier per 64-t tile (m97/T2/rule-21 recipe).
//  - glds16 prefetch for tile n+1 issues at top of iter n with NO in-wave
//    register dependency -> latency hides under iter n's compute; the
//    end-of-iter barrier drains it (r12-r14's reg-staging pitfalls avoided).
//  - dbuf makes one barrier serve both "prefetch ready" and "safe to
//    overwrite" (buffer reused 2 tiles later).
//  - LDS linear stride 64 (no pad); reads swizzle 16B-block ^= (row&7):
//    glds writes linear (conflict-free), reads 2 lanes/group (free, m136).
//    Source-side: per-lane GLOBAL addr fetches the element belonging at the
//    lane's linear LDS slot (involution: blk' = blk ^ (r&7)).
//  - P buffer also stride-64 + XOR (write 2-way, read 2-way) -> the constant
//    3.78M bank-conflict cycles (13% of runtime) should vanish.
//  - LDS = 2*8192(K) + 2*8192(V) + 8192(Ps) = 40960 B -> 4 blocks/CU; grid
//    1024 = 4/CU -> all blocks resident in one generation.
// Kept: ones-trick l on MFMA pipe (r15), v_perm trunc-pack, fixed-max
// softmax, qt reversed (diagonal-heavy first).

#define MFMA_BF16 __builtin_amdgcn_mfma_f32_16x16x32_bf16

template <bool MASKED>
__device__ __forceinline__ void attn_step(int t0, int q0, int wq, int wt,
    const short8 (&qa)[2][2],
    const unsigned short* Ks, const unsigned short* Vs, unsigned short* Psq,
    floatx4 (&o)[2][4], floatx4 (&o_l)[2], int lrow, int lgrp) {
  const int twbase = wt * 32;   // this wave's 32-t slice of the 64-t tile
  const int sw = lrow & 7;      // XOR swizzle index (row&7 for all our rows)
#pragma unroll
  for (int tb = 0; tb < 2; ++tb) {
    const int R = twbase + tb * 16 + lrow;
    short8 kb0 = *(const short8*)&Ks[R * 64 + ((lgrp ^ sw) * 8)];
    short8 kb1 = *(const short8*)&Ks[R * 64 + (((lgrp + 4) ^ sw) * 8)];
#pragma unroll
    for (int qb = 0; qb < 2; ++qb) {
      floatx4 st = {};
      st = MFMA_BF16(kb0, qa[qb][0], st, 0, 0, 0);
      st = MFMA_BF16(kb1, qa[qb][1], st, 0, 0, 0);
      // C layout: lane holds t = twbase+tb*16+lgrp*4+r (row), q = qb*16+lrow (col)
      float p0 = exp2f(st[0]), p1 = exp2f(st[1]);
      float p2 = exp2f(st[2]), p3 = exp2f(st[3]);
      if (MASKED) {
        const int qcol = q0 + wq * 32 + qb * 16 + lrow;
        const int tbase = t0 + twbase + tb * 16 + lgrp * 4;
        p0 = (tbase     <= qcol) ? p0 : 0.0f;
        p1 = (tbase + 1 <= qcol) ? p1 : 0.0f;
        p2 = (tbase + 2 <= qcol) ? p2 : 0.0f;
        p3 = (tbase + 3 <= qcol) ? p3 : 0.0f;
      }
      // trunc-pack two bf16 highs per v_perm_b32
      uint2 pu;
      pu.x = __builtin_amdgcn_perm(fbits(p1), fbits(p0), 0x07060302u);
      pu.y = __builtin_amdgcn_perm(fbits(p3), fbits(p2), 0x07060302u);
      // P store: logical 16B-block Bb of row q, XOR-swizzled; 8B half = lgrp&1
      const int Bb = wt * 4 + tb * 2 + (lgrp >> 1);
      *(uint2*)&Psq[(qb * 16 + lrow) * 64 + ((Bb ^ sw) * 8) + (lgrp & 1) * 4] = pu;
    }
  }
  // PV over this wave's 32-t slice: A = P[q][t] (LDS, swizzled), B = V[t][hd].
  // l via B=ones: o_l[qb][r] = partial sum_t P[q][t], same layout as o.
  const short8 vones = { 0x3F80, 0x3F80, 0x3F80, 0x3F80,
                         0x3F80, 0x3F80, 0x3F80, 0x3F80 };  // bf16 1.0 x8
  const int pblk = (wt * 4 + lgrp) ^ sw;   // logical t-block wt*4+lgrp, swizzled
  short8 pa0 = *(const short8*)&Psq[lrow * 64 + pblk * 8];
  short8 pa1 = *(const short8*)&Psq[(16 + lrow) * 64 + pblk * 8];
  o_l[0] = MFMA_BF16(pa0, vones, o_l[0], 0, 0, 0);
  o_l[1] = MFMA_BF16(pa1, vones, o_l[1], 0, 0, 0);
#pragma unroll
  for (int hb = 0; hb < 4; ++hb) {
    short8 vb = *(const short8*)&Vs[(hb * 16 + lrow) * 64 + pblk * 8];
    o[0][hb] = MFMA_BF16(pa0, vb, o[0][hb], 0, 0, 0);
    o[1][hb] = MFMA_BF16(pa1, vb, o[1][hb], 0, 0, 0);
  }
}

// grid (32 bh, 32 qt): linear id % 8 = bh % 8 -> one bh per XCD (L2 locality).
// qt reversed: heavy diagonal blocks first. block 256 = 4 waves (2q x 2t).
// LDS 40960 B = 20 x 2KiB -> 4 blocks/CU exactly; grid 1024 = 4/CU resident.
__global__ __launch_bounds__(256) void k_flash(const unsigned short* __restrict__ q_n,
                                               const unsigned short* __restrict__ k_n,
                                               const unsigned short* __restrict__ VT,
                                               unsigned short* __restrict__ ctx) {
  const int S = 2048, D = 1024;
  const int bh = blockIdx.x, b = bh >> 4, h = bh & 15;
  const int qt = 31 - (int)blockIdx.y;
  const int q0 = qt * 64;
  const int tid = threadIdx.x, wave = tid >> 6, lane = tid & 63;
  const int wq = wave >> 1, wt = wave & 1;
  const int lrow = lane & 15, lgrp = lane >> 4;

  __shared__ __align__(16) unsigned char smem[40960];
  unsigned short* Ks0 = (unsigned short*)smem;              // 64*64*2 = 8192
  unsigned short* Ks1 = (unsigned short*)(smem + 8192);
  unsigned short* Vs0 = (unsigned short*)(smem + 16384);
  unsigned short* Vs1 = (unsigned short*)(smem + 24576);
  unsigned short* Psq = (unsigned short*)(smem + 32768) + wq * 32 * 64;  // 2*4096
  // tail aliases (dead after final loop barrier): buf @0, Lbuf after
  float* buf  = (float*)smem;                               // 2*32*68*4 = 17408
  float* Lbuf = (float*)(smem + 17408);                     // 64 floats -> 17664

  const unsigned short* kg = k_n + (size_t)(b * S) * D + h * 64;
  const unsigned short* vg = VT + (size_t)bh * 64 * S;

  // glds16 staging: each wave stages 8 K-rows + 8 V-rows per glds16 x2 each.
  // Per-lane GLOBAL addr pre-swizzled so linear LDS holds blk' = blk^(r&7).
  const int r0 = wave * 8 + (lane >> 3);        // row within tile (wave*8 ≡ 0 mod 8)
  const int sblk = (lane & 7) ^ (r0 & 7);       // source 16B-block for this lane
  const unsigned short* kst0 = kg + (size_t)r0 * D + sblk * 8;
  const unsigned short* kst1 = kg + (size_t)(r0 + 32) * D + sblk * 8;
  const unsigned short* vst0 = vg + (size_t)r0 * S + sblk * 8;
  const unsigned short* vst1 = vg + (size_t)(r0 + 32) * S + sblk * 8;
  const int ldso0 = wave * 512;                 // shorts: 8 rows * 64
  const int ldso1 = 2048 + wave * 512;

#define STAGE(tn, Ksb, Vsb) do {                       \
    glds16(kst0 + (size_t)(tn) * D, (Ksb) + ldso0);    \
    glds16(kst1 + (size_t)(tn) * D, (Ksb) + ldso1);    \
    glds16(vst0 + (tn),             (Vsb) + ldso0);    \
    glds16(vst1 + (tn),             (Vsb) + ldso1);    \
  } while (0)

  // qa[qb]: B-frag, lane n = q = q0 + wq*32 + qb*16 + lrow, k = hd = lgrp*8+j (+32)
  short8 qa[2][2];
#pragma unroll
  for (int qb = 0; qb < 2; ++qb) {
    const unsigned short* qp =
        q_n + (size_t)(b * S + q0 + wq * 32 + qb * 16 + lrow) * D + h * 64;
    qa[qb][0] = *(const short8*)(qp + lgrp * 8);
    qa[qb][1] = *(const short8*)(qp + 32 + lgrp * 8);
  }
  floatx4 o[2][4] = {};
  floatx4 o_l[2] = {};

  // prologue: stage tile 0 into buffer 0; barrier drains vmcnt (m97 semantics)
  STAGE(0, Ks0, Vs0);
  __syncthreads();

  const int tend = q0 + 64;
  for (int t0 = 0; t0 < tend; t0 += 64) {
    const bool odd = (t0 >> 6) & 1;
    unsigned short* Ksc = odd ? Ks1 : Ks0;
    unsigned short* Vsc = odd ? Vs1 : Vs0;
    if (t0 + 64 < tend)                      // async prefetch next tile
      STAGE(t0 + 64, odd ? Ks0 : Ks1, odd ? Vs0 : Vs1);
    if (t0 + 64 <= q0)
      attn_step<false>(t0, q0, wq, wt, qa, Ksc, Vsc, Psq, o, o_l, lrow, lgrp);
    else
      attn_step<true>(t0, q0, wq, wt, qa, Ksc, Vsc, Psq, o, o_l, lrow, lgrp);
    __syncthreads();   // drains prefetch AND protects buffer reuse (dbuf)
  }
#undef STAGE

  // ---- tail: combine the wt pair (O and l are t-partial per wave) ----
  // o_l[qb][r] = partial l for q-row qb*16+lgrp*4+r, replicated over lrow.
  if (wt == 1) {
    if (lrow == 0) {
#pragma unroll
      for (int qb = 0; qb < 2; ++qb)
#pragma unroll
        for (int r = 0; r < 4; ++r)
          Lbuf[wq * 32 + qb * 16 + lgrp * 4 + r] = o_l[qb][r];
    }
    float* bf = buf + wq * 32 * 68;
#pragma unroll
    for (int qb = 0; qb < 2; ++qb)
#pragma unroll
      for (int hb = 0; hb < 4; ++hb)
#pragma unroll
        for (int r = 0; r < 4; ++r)
          bf[(qb * 16 + lgrp * 4 + r) * 68 + hb * 16 + lrow] = o[qb][hb][r];
  }
  __syncthreads();
  if (wt == 0) {
    float* bf = buf + wq * 32 * 68;
#pragma unroll
    for (int qb = 0; qb < 2; ++qb)
#pragma unroll
      for (int hb = 0; hb < 4; ++hb)
#pragma unroll
        for (int r = 0; r < 4; ++r)
          o[qb][hb][r] += bf[(qb * 16 + lgrp * 4 + r) * 68 + hb * 16 + lrow];
    unsigned short* op = ctx + (size_t)(b * S + q0 + wq * 32) * D + h * 64;
#pragma unroll
    for (int qb = 0; qb < 2; ++qb)
#pragma unroll
      for (int r = 0; r < 4; ++r) {
        float inv = 1.0f / (o_l[qb][r] + Lbuf[wq * 32 + qb * 16 + lgrp * 4 + r]);
        int row = qb * 16 + lgrp * 4 + r;
#pragma unroll
        for (int hb = 0; hb < 4; ++hb)
          op[(size_t)row * D + hb * 16 + lrow] = f2bf(o[qb][hb][r] * inv);
      }
  }
}

// ---------------------------------- launch ----------------------------------
extern "C" void kernel_launch(void* const* d_in, const int* in_sizes, int n_in,
                              void* d_out, int out_size, void* d_ws, size_t ws_size,
                              hipStream_t stream) {
  const float* x       = (const float*)d_in[0];   // [2,2048,1024] fp32
  const float* W_qkv   = (const float*)d_in[1];   // [1024,3072] fp32
  const float* q_scale = (const float*)d_in[2];   // [1024] fp32
  const float* k_scale = (const float*)d_in[3];   // [1024] fp32
  const float* W_out   = (const float*)d_in[4];   // [1024,1024] fp32
  float* out = (float*)d_out;                     // [2,2048,1024] fp32
  char* ws = (char*)d_ws;
  unsigned short* WT_qkv = (unsigned short*)(ws + 0);         //  6291456
  unsigned short* WT_out = (unsigned short*)(ws + 6291456);   //  2097152
  unsigned short* qkv    = (unsigned short*)(ws + 8388608);   // 25165824
  unsigned short* q_nb   = (unsigned short*)(ws + 33554432);  //  8388608
  unsigned short* k_nb   = (unsigned short*)(ws + 41943040);  //  8388608
  unsigned short* VT     = (unsigned short*)(ws + 50331648);  //  8388608
  unsigned short* x_bf   = (unsigned short*)(ws + 58720256);  //  8388608 -> 64 MiB
  unsigned short* ctx    = qkv;  // alias: qkv dead after k_lnv

  k_prep<<<8192, 256, 0, stream>>>(x, W_qkv, W_out, x_bf, WT_qkv, WT_out);
  k_gemm_bt<128, false><<<dim3(32, 24), 256, 0, stream>>>(x_bf, WT_qkv, qkv, 4096, 3072, 1024);
  k_lnv<<<8192, 256, 0, stream>>>(qkv, q_scale, k_scale, q_nb, k_nb, VT);
  k_flash<<<dim3(32, 32), 256, 0, stream>>>(q_nb, k_nb, VT, ctx);
  k_gemm_bt<64, true><<<dim3(64, 8), 256, 0, stream>>>(ctx, WT_out, out, 4096, 1024, 1024);
}

// Round 8
// 182.566 us; speedup vs baseline: 1.0661x; 1.0161x over previous
//
#include <hip/hip_runtime.h>
#include <cstdint>
#include <cstddef>

typedef __attribute__((ext_vector_type(8))) short short8;   // 8 bf16 = 4 VGPRs (MFMA A/B frag)
typedef __attribute__((ext_vector_type(4))) float floatx4;  // MFMA C/D frag

__device__ __forceinline__ float bf2f(unsigned short u) {
  union { unsigned int i; float f; } c; c.i = ((unsigned int)u) << 16; return c.f;
}
__device__ __forceinline__ unsigned short f2bf(float f) {
  union { float f; unsigned int i; } c; c.f = f;
  unsigned int r = c.i + 0x7fffu + ((c.i >> 16) & 1u);  // round-nearest-even
  return (unsigned short)(r >> 16);
}
__device__ __forceinline__ unsigned int fbits(float f) {
  union { float f; unsigned int i; } c; c.f = f; return c.i;
}

// async global->LDS, 16 B per lane; LDS dest = wave-uniform base + lane*16 (m97/m104)
__device__ __forceinline__ void glds16(const unsigned short* g, unsigned short* l) {
  __builtin_amdgcn_global_load_lds((const __attribute__((address_space(1))) void*)g,
                                   (__attribute__((address_space(3))) void*)l, 16, 0, 0);
}

// ---- 32x32 transpose+cvt tile helper (256 threads, 4 rows/thread) ----
__device__ __forceinline__ void tr_tile(const float* __restrict__ in,
                                        unsigned short* __restrict__ out,
                                        int R, int C, int bx, int by, int tid,
                                        unsigned short (*t)[33]) {
  const int cx = tid & 31, rl = tid >> 5;
#pragma unroll
  for (int i = 0; i < 4; ++i)
    t[rl + i * 8][cx] = f2bf(in[(size_t)(by * 32 + rl + i * 8) * C + bx * 32 + cx]);
  __syncthreads();
  const int oc = by * 32 + cx;
#pragma unroll
  for (int i = 0; i < 4; ++i)
    out[(size_t)(bx * 32 + rl + i * 8) * R + oc] = t[cx][rl + i * 8];
}

// ---- fused prep: W_qkv^T (3072 blks) + W_out^T (1024 blks) + x cvt (4096 blks) ----
__global__ __launch_bounds__(256) void k_prep(const float* __restrict__ x,
                                              const float* __restrict__ Wq,
                                              const float* __restrict__ Wo,
                                              unsigned short* __restrict__ x_bf,
                                              unsigned short* __restrict__ WTq,
                                              unsigned short* __restrict__ WTo) {
  __shared__ unsigned short t[32][33];
  const int bid = blockIdx.x, tid = threadIdx.x;
  if (bid < 3072) {
    tr_tile(Wq, WTq, 1024, 3072, bid % 96, bid / 96, tid, t);
  } else if (bid < 4096) {
    int v = bid - 3072;
    tr_tile(Wo, WTo, 1024, 1024, v & 31, v >> 5, tid, t);
  } else {
    int i = (bid - 4096) * 256 + tid;
    float4 v = ((const float4*)x)[i];
    ushort4 o = { f2bf(v.x), f2bf(v.y), f2bf(v.z), f2bf(v.w) };
    ((ushort4*)x_bf)[i] = o;
  }
}

// ---------------- GEMM: C[M][N] = A[M][K] * BT[N][K]^T, bf16 in ----------------
// m97 structure + r9: BK=64 via TWO glds16 buffers -> one barrier pair per
// 64-K instead of 32-K (halves barrier-drain stalls). LDS 32 KB.
template <int MT, bool F32OUT>
__global__ __launch_bounds__(256) void k_gemm_bt(const unsigned short* __restrict__ A,
                                                 const unsigned short* __restrict__ BT,
                                                 void* __restrict__ Cout,
                                                 int M, int N, int K) {
  constexpr int NI = MT / 32;  // per-wave m-frag count (4 or 2)
  __shared__ unsigned short As[2][MT * 32];
  __shared__ unsigned short Bs[2][128 * 32];
  const int bm = blockIdx.x * MT, bn = blockIdx.y * 128;
  const int tid = threadIdx.x;
  const int wave = tid >> 6, lane = tid & 63;
  const int wm = (wave & 1) * (MT / 2), wn = (wave >> 1) * 64;
  const int lrow = lane & 15, lgrp = lane >> 4;
  floatx4 acc[NI][4] = {};

  const int lr4 = lane >> 2, lc8 = (lane & 3) * 8;
  const int br0 = wave * 32;
  const unsigned short* Bg0 = BT + (size_t)(bn + br0 + lr4) * K + lc8;
  const unsigned short* Bg1 = BT + (size_t)(bn + br0 + 16 + lr4) * K + lc8;
  const int ar0 = wave * (MT / 4);
  const unsigned short* Ag0 = A + (size_t)(bm + ar0 + lr4) * K + lc8;
  const unsigned short* Ag1 = A + (size_t)(bm + ar0 + 16 + lr4) * K + lc8;  // MT==128 only

  for (int k0 = 0; k0 < K; k0 += 64) {
#pragma unroll
    for (int u = 0; u < 2; ++u) {
      const int ko = k0 + u * 32;
      glds16(Ag0 + ko, &As[u][ar0 * 32]);
      if (MT == 128) glds16(Ag1 + ko, &As[u][(ar0 + 16) * 32]);
      glds16(Bg0 + ko, &Bs[u][br0 * 32]);
      glds16(Bg1 + ko, &Bs[u][(br0 + 16) * 32]);
    }
    __syncthreads();   // drains vmcnt (glds) before any wave reads LDS
#pragma unroll
    for (int u = 0; u < 2; ++u) {
      short8 a[NI], bfr[4];
#pragma unroll
      for (int i = 0; i < NI; ++i)
        a[i] = *(const short8*)&As[u][(wm + i * 16 + lrow) * 32 + lgrp * 8];
#pragma unroll
      for (int j = 0; j < 4; ++j)
        bfr[j] = *(const short8*)&Bs[u][(wn + j * 16 + lrow) * 32 + lgrp * 8];
#pragma unroll
      for (int i = 0; i < NI; ++i)
#pragma unroll
        for (int j = 0; j < 4; ++j)
          acc[i][j] = __builtin_amdgcn_mfma_f32_16x16x32_bf16(a[i], bfr[j], acc[i][j], 0, 0, 0);
    }
    __syncthreads();
  }
#pragma unroll
  for (int i = 0; i < NI; ++i)
#pragma unroll
    for (int j = 0; j < 4; ++j)
#pragma unroll
      for (int r = 0; r < 4; ++r) {
        int m = bm + wm + i * 16 + lgrp * 4 + r;
        int n = bn + wn + j * 16 + lrow;
        if (F32OUT)
          ((float*)Cout)[(size_t)m * N + n] = acc[i][j][r];
        else
          ((unsigned short*)Cout)[(size_t)m * N + n] = f2bf(acc[i][j][r]);
      }
}

// ---- fused LN (4096 blks) + V transpose (4096 blks); both read qkv ----
// LN: q out folded by 0.125*log2(e) so flash uses exp2 directly.
__global__ __launch_bounds__(256) void k_lnv(const unsigned short* __restrict__ qkv,
                                             const float* __restrict__ q_scale,
                                             const float* __restrict__ k_scale,
                                             unsigned short* __restrict__ q_n,
                                             unsigned short* __restrict__ k_n,
                                             unsigned short* __restrict__ VT) {
  const int bid = blockIdx.x, tid = threadIdx.x;
  if (bid < 4096) {
    const int tok = bid;
    const int wave = tid >> 6, lane = tid & 63;
    __shared__ float red[2][4];
    const unsigned short* row = qkv + (size_t)tok * 3072;
#pragma unroll
    for (int seg = 0; seg < 2; ++seg) {
      const unsigned short* p  = row + seg * 1024;
      const float* sc = seg ? k_scale : q_scale;
      unsigned short* outp = (seg ? k_n : q_n) + (size_t)tok * 1024;
      ushort4 u = *(const ushort4*)&p[tid * 4];
      float xv[4] = { bf2f(u.x), bf2f(u.y), bf2f(u.z), bf2f(u.w) };
      float sum = xv[0] + xv[1] + xv[2] + xv[3];
      float sq  = xv[0]*xv[0] + xv[1]*xv[1] + xv[2]*xv[2] + xv[3]*xv[3];
      for (int off = 32; off; off >>= 1) {
        sum += __shfl_down(sum, off, 64);
        sq  += __shfl_down(sq,  off, 64);
      }
      if (lane == 0) { red[0][wave] = sum; red[1][wave] = sq; }
      __syncthreads();
      sum = red[0][0] + red[0][1] + red[0][2] + red[0][3];
      sq  = red[1][0] + red[1][1] + red[1][2] + red[1][3];
      __syncthreads();
      float mean = sum * (1.0f / 1024.0f);
      float var  = sq * (1.0f / 1024.0f) - mean * mean;
      float rstd = rsqrtf(var + 1e-6f);
      if (seg == 0) rstd *= 0.18033688011112042f;  // 0.125 * log2(e)
      float4 su = *(const float4*)&sc[tid * 4];
      ushort4 o;
      o.x = f2bf((xv[0] - mean) * rstd * su.x);
      o.y = f2bf((xv[1] - mean) * rstd * su.y);
      o.z = f2bf((xv[2] - mean) * rstd * su.z);
      o.w = f2bf((xv[3] - mean) * rstd * su.w);
      *(ushort4*)&outp[tid * 4] = o;
    }
  } else {
    // V transpose tile: v-part [b,s,h*64+hd] -> VT[(b*16+h)*64+hd][s]
    __shared__ unsigned short t[32][33];
    const int v = bid - 4096;
    const int bh = v & 31, b = bh >> 4, h = bh & 15;
    const int sy = (v >> 5) & 63, hx = v >> 11;   // s-tile 0..63, hd-tile 0..1
    const int cx = tid & 31, rl = tid >> 5;
#pragma unroll
    for (int i = 0; i < 4; ++i)
      t[rl + i * 8][cx] =
        qkv[(size_t)(b * 2048 + sy * 32 + rl + i * 8) * 3072 + 2048 + h * 64 + hx * 32 + cx];
    __syncthreads();
#pragma unroll
    for (int i = 0; i < 4; ++i)
      VT[((size_t)bh * 64 + hx * 32 + rl + i * 8) * 2048 + sy * 32 + cx] = t[cx][rl + i * 8];
  }
}

// ------------------------------ flash attention ------------------------------
// r18 = EXACT r15 structure (proven 45.0us: inline K+V staging, 2 barriers per
// 128-t step, LDS 53248 -> 3 blocks/CU, ones-trick l on MFMA pipe, v_perm
// trunc-pack, fixed-max softmax) + T5 s_setprio around the MFMA clusters.
// m191 evidence: +4-7% on attn where independent blocks co-reside per CU at
// different phases (our case: 3 blocks/CU, no inter-block sync). m190: hurts
// barrier-locked GEMM — NOT applied to k_gemm_bt.
// r17 post-mortem: XOR swizzle cut conflicts 3.78M->1.08M but added VALU
// (VALUBusy 50->61) and net -3.6us — conflicts here are mostly 2-way (free,
// m136); reverted. r16: halved tile doubled exposed stage latency; reverted.
// All b128 LDS strides multiples of 8 shorts (16 B) — r6 lesson.

#define KS_STRIDE 72   // 144 B = 9*16
#define VS_STRIDE 136  // 272 B = 17*16
#define PS_STRIDE 136  // shared [32 q][128 t] pad->136

#define MFMA_BF16 __builtin_amdgcn_mfma_f32_16x16x32_bf16

template <bool MASKED>
__device__ __forceinline__ void attn_step(int t0, int q0, int wq, int wt,
    const short8 (&qa)[2][2],
    const unsigned short* Ks, const unsigned short* Vs, unsigned short* Psq,
    floatx4 (&o)[2][4], floatx4 (&o_l)[2], int lrow, int lgrp) {
  const int twbase = wt * 64;
#pragma unroll
  for (int tb = 0; tb < 4; ++tb) {
    short8 kb0 = *(const short8*)&Ks[(twbase + tb * 16 + lrow) * KS_STRIDE + lgrp * 8];
    short8 kb1 = *(const short8*)&Ks[(twbase + tb * 16 + lrow) * KS_STRIDE + 32 + lgrp * 8];
#pragma unroll
    for (int qb = 0; qb < 2; ++qb) {
      floatx4 st = {};
      __builtin_amdgcn_s_setprio(1);          // T5: favor this wave's MFMA burst
      st = MFMA_BF16(kb0, qa[qb][0], st, 0, 0, 0);
      st = MFMA_BF16(kb1, qa[qb][1], st, 0, 0, 0);
      __builtin_amdgcn_s_setprio(0);
      // C layout: lane holds t = twbase+tb*16+lgrp*4+r (row), q = qb*16+lrow (col)
      float p0 = exp2f(st[0]), p1 = exp2f(st[1]);
      float p2 = exp2f(st[2]), p3 = exp2f(st[3]);
      if (MASKED) {
        const int qcol = q0 + wq * 32 + qb * 16 + lrow;
        const int tbase = t0 + twbase + tb * 16 + lgrp * 4;
        p0 = (tbase     <= qcol) ? p0 : 0.0f;
        p1 = (tbase + 1 <= qcol) ? p1 : 0.0f;
        p2 = (tbase + 2 <= qcol) ? p2 : 0.0f;
        p3 = (tbase + 3 <= qcol) ? p3 : 0.0f;
      }
      // trunc-pack two bf16 highs in one v_perm_b32 each (no VALU l-accum)
      uint2 pu;
      pu.x = __builtin_amdgcn_perm(fbits(p1), fbits(p0), 0x07060302u);
      pu.y = __builtin_amdgcn_perm(fbits(p3), fbits(p2), 0x07060302u);
      *(uint2*)&Psq[(qb * 16 + lrow) * PS_STRIDE + twbase + tb * 16 + lgrp * 4] = pu;
    }
  }
  // PV over this wave's 64-t slice: A = P[q][t] (own half), B = V[t][hd].
  // l via B=ones: o_l[qb][r] accumulates sum_t P[q = qb*16+lgrp*4+r][t],
  // replicated across lrow — identical layout to o.
  const short8 vones = { 0x3F80, 0x3F80, 0x3F80, 0x3F80,
                         0x3F80, 0x3F80, 0x3F80, 0x3F80 };  // bf16 1.0 x8
#pragma unroll
  for (int kk = 0; kk < 2; ++kk) {
    short8 pa0 = *(const short8*)&Psq[lrow * PS_STRIDE + twbase + kk * 32 + lgrp * 8];
    short8 pa1 = *(const short8*)&Psq[(16 + lrow) * PS_STRIDE + twbase + kk * 32 + lgrp * 8];
    __builtin_amdgcn_s_setprio(1);            // T5: PV MFMA cluster
    o_l[0] = MFMA_BF16(pa0, vones, o_l[0], 0, 0, 0);
    o_l[1] = MFMA_BF16(pa1, vones, o_l[1], 0, 0, 0);
#pragma unroll
    for (int hb = 0; hb < 4; ++hb) {
      short8 vb = *(const short8*)&Vs[(hb * 16 + lrow) * VS_STRIDE + twbase + kk * 32 + lgrp * 8];
      o[0][hb] = MFMA_BF16(pa0, vb, o[0][hb], 0, 0, 0);
      o[1][hb] = MFMA_BF16(pa1, vb, o[1][hb], 0, 0, 0);
    }
    __builtin_amdgcn_s_setprio(0);
  }
}

// grid (32 bh, 32 qt): linear id % 8 = bh % 8 -> one bh per XCD (L2 locality).
// qt reversed: heavy diagonal blocks first. block 256 = 4 waves (2q x 2t).
// LDS 53248 B = 26 x 2KiB -> 3 blocks/CU (159744 <= 163840).
__global__ __launch_bounds__(256) void k_flash(const unsigned short* __restrict__ q_n,
                                               const unsigned short* __restrict__ k_n,
                                               const unsigned short* __restrict__ VT,
                                               unsigned short* __restrict__ ctx) {
  const int S = 2048, D = 1024;
  const int bh = blockIdx.x, b = bh >> 4, h = bh & 15;
  const int qt = 31 - (int)blockIdx.y;
  const int q0 = qt * 64;
  const int tid = threadIdx.x, wave = tid >> 6, lane = tid & 63;
  const int wq = wave >> 1, wt = wave & 1;
  const int lrow = lane & 15, lgrp = lane >> 4;

  __shared__ __align__(16) unsigned char smem[53248];
  unsigned short* Ks  = (unsigned short*)smem;                    // 128*72*2 = 18432
  unsigned short* Vs  = (unsigned short*)(smem + 18432);          //  64*136*2 = 17408
  unsigned short* Psq = (unsigned short*)(smem + 35840) + wq * 32 * PS_STRIDE; // 2*8704
  // tail aliases (dead regions after loop): buf over Ks, Lbuf over Vs start
  float* buf  = (float*)smem;                                     // 2*32*68*4 = 17408
  float* Lbuf = (float*)(smem + 17408);                           // 64 floats

  const unsigned short* kg = k_n + (size_t)(b * S) * D + h * 64;
  const unsigned short* vg = VT + (size_t)bh * 64 * S;
  const int ksr = tid >> 3, ksc = (tid & 7) * 8;    // K staging: 32 rows/pass
  const int vsr = tid >> 4, vsc = (tid & 15) * 8;   // V staging: 16 rows/pass

  // qa[qb]: B-frag, lane n = q = q0 + wq*32 + qb*16 + lrow, k = hd = lgrp*8+j (+32)
  short8 qa[2][2];
#pragma unroll
  for (int qb = 0; qb < 2; ++qb) {
    const unsigned short* qp =
        q_n + (size_t)(b * S + q0 + wq * 32 + qb * 16 + lrow) * D + h * 64;
    qa[qb][0] = *(const short8*)(qp + lgrp * 8);
    qa[qb][1] = *(const short8*)(qp + 32 + lgrp * 8);
  }
  floatx4 o[2][4] = {};
  floatx4 o_l[2] = {};

  const int tend = q0 + 64;
  for (int t0 = 0; t0 < tend; t0 += 128) {
#pragma unroll
    for (int j = 0; j < 4; ++j) {
      int r = ksr + j * 32;
      *(int4*)&Ks[r * KS_STRIDE + ksc] = *(const int4*)(kg + (size_t)(t0 + r) * D + ksc);
    }
#pragma unroll
    for (int j = 0; j < 4; ++j) {
      int r = vsr + j * 16;
      *(int4*)&Vs[r * VS_STRIDE + vsc] = *(const int4*)(vg + (size_t)r * S + t0 + vsc);
    }
    __syncthreads();
    const bool half = (tend - t0) < 128;   // last 64-t step: wt=1's slice is void
    if (!(half && wt == 1)) {
      if (t0 + 128 <= q0)
        attn_step<false>(t0, q0, wq, wt, qa, Ks, Vs, Psq, o, o_l, lrow, lgrp);
      else
        attn_step<true>(t0, q0, wq, wt, qa, Ks, Vs, Psq, o, o_l, lrow, lgrp);
    }
    __syncthreads();
  }

  // ---- tail: combine the wt pair (O and l are t-partial per wave) ----
  // o_l[qb][r] = partial l for q-row qb*16+lgrp*4+r, replicated over lrow.
  if (wt == 1) {
    if (lrow == 0) {
#pragma unroll
      for (int qb = 0; qb < 2; ++qb)
#pragma unroll
        for (int r = 0; r < 4; ++r)
          Lbuf[wq * 32 + qb * 16 + lgrp * 4 + r] = o_l[qb][r];
    }
    float* bf = buf + wq * 32 * 68;
#pragma unroll
    for (int qb = 0; qb < 2; ++qb)
#pragma unroll
      for (int hb = 0; hb < 4; ++hb)
#pragma unroll
        for (int r = 0; r < 4; ++r)
          bf[(qb * 16 + lgrp * 4 + r) * 68 + hb * 16 + lrow] = o[qb][hb][r];
  }
  __syncthreads();
  if (wt == 0) {
    float* bf = buf + wq * 32 * 68;
#pragma unroll
    for (int qb = 0; qb < 2; ++qb)
#pragma unroll
      for (int hb = 0; hb < 4; ++hb)
#pragma unroll
        for (int r = 0; r < 4; ++r)
          o[qb][hb][r] += bf[(qb * 16 + lgrp * 4 + r) * 68 + hb * 16 + lrow];
    unsigned short* op = ctx + (size_t)(b * S + q0 + wq * 32) * D + h * 64;
#pragma unroll
    for (int qb = 0; qb < 2; ++qb)
#pragma unroll
      for (int r = 0; r < 4; ++r) {
        float inv = 1.0f / (o_l[qb][r] + Lbuf[wq * 32 + qb * 16 + lgrp * 4 + r]);
        int row = qb * 16 + lgrp * 4 + r;
#pragma unroll
        for (int hb = 0; hb < 4; ++hb)
          op[(size_t)row * D + hb * 16 + lrow] = f2bf(o[qb][hb][r] * inv);
      }
  }
}

// ---------------------------------- launch ----------------------------------
extern "C" void kernel_launch(void* const* d_in, const int* in_sizes, int n_in,
                              void* d_out, int out_size, void* d_ws, size_t ws_size,
                              hipStream_t stream) {
  const float* x       = (const float*)d_in[0];   // [2,2048,1024] fp32
  const float* W_qkv   = (const float*)d_in[1];   // [1024,3072] fp32
  const float* q_scale = (const float*)d_in[2];   // [1024] fp32
  const float* k_scale = (const float*)d_in[3];   // [1024] fp32
  const float* W_out   = (const float*)d_in[4];   // [1024,1024] fp32
  float* out = (float*)d_out;                     // [2,2048,1024] fp32
  char* ws = (char*)d_ws;
  unsigned short* WT_qkv = (unsigned short*)(ws + 0);         //  6291456
  unsigned short* WT_out = (unsigned short*)(ws + 6291456);   //  2097152
  unsigned short* qkv    = (unsigned short*)(ws + 8388608);   // 25165824
  unsigned short* q_nb   = (unsigned short*)(ws + 33554432);  //  8388608
  unsigned short* k_nb   = (unsigned short*)(ws + 41943040);  //  8388608
  unsigned short* VT     = (unsigned short*)(ws + 50331648);  //  8388608
  unsigned short* x_bf   = (unsigned short*)(ws + 58720256);  //  8388608 -> 64 MiB
  unsigned short* ctx    = qkv;  // alias: qkv dead after k_lnv

  k_prep<<<8192, 256, 0, stream>>>(x, W_qkv, W_out, x_bf, WT_qkv, WT_out);
  k_gemm_bt<128, false><<<dim3(32, 24), 256, 0, stream>>>(x_bf, WT_qkv, qkv, 4096, 3072, 1024);
  k_lnv<<<8192, 256, 0, stream>>>(qkv, q_scale, k_scale, q_nb, k_nb, VT);
  k_flash<<<dim3(32, 32), 256, 0, stream>>>(q_nb, k_nb, VT, ctx);
  k_gemm_bt<64, true><<<dim3(64, 8), 256, 0, stream>>>(ctx, WT_out, out, 4096, 1024, 1024);
}